// Round 5
// baseline (301.267 us; speedup 1.0000x reference)
//
#include <hip/hip_runtime.h>
#include <stdint.h>

// int4 grouped-quant GEMM: out[64][28672] = x[64][8192] . W^T + bias
// W packed [N][K/2] int32, one byte/int32 = 2 nibbles (low = even k), zp = 8,
// per-128-k scales. fp16 ref -> harness gives x/scales/bias/out as FP32.
// HBM-bound on the 470 MB weight stream (~75 us @ 6.3 TB/s achievable).
// Round-5: ZERO barriers. x pre-packed to A-fragment order (xpack) and read
// straight from L2 with a rolling 4-kstep register window; weights in a
// depth-2 register group pipeline. No LDS -> no vmcnt(0) drains anywhere.

typedef __attribute__((ext_vector_type(8))) short short8;  // MFMA bf16 A/B frag
typedef __attribute__((ext_vector_type(4))) float f32x4;   // MFMA C/D frag
typedef __attribute__((ext_vector_type(4))) int   i32x4;

struct WGrp { i32x4 w0, w1, w2, w3; float s; };  // one 128-k weight group / lane
struct XS   { short8 x0, x1, x2, x3; };          // one 32-k step's A-frags (4 m-tiles)

static __device__ __forceinline__ short bf(float f) {
    return __builtin_bit_cast(short, (__bf16)f);   // HW v_cvt, RNE
}

// One 128-k weight group: 16 int32/lane, nontemporal (streamed once).
static __device__ __forceinline__ WGrp load_grp(const int* __restrict__ wrow,
                                                const float* __restrict__ srow, int g) {
    WGrp r;
    const i32x4* p = (const i32x4*)(wrow + g * 64);
    r.w0 = __builtin_nontemporal_load(p);
    r.w1 = __builtin_nontemporal_load(p + 4);
    r.w2 = __builtin_nontemporal_load(p + 8);
    r.w3 = __builtin_nontemporal_load(p + 12);
    r.s  = srow[g];
    return r;
}

// A-frags for one kstep from frag-ordered xf (coalesced lane*16, L2-hit).
static __device__ __forceinline__ XS load_xs(const char* p) {
    XS r;
    r.x0 = *(const short8*)(p);
    r.x1 = *(const short8*)(p + 1024);
    r.x2 = *(const short8*)(p + 2048);
    r.x3 = *(const short8*)(p + 3072);
    return r;
}

// One 32-k MFMA step: dequant B, 4 MFMAs from the window slot, then re-issue
// the slot's loads for the NEXT group (anti-dep: loads issue after MFMA reads).
static __device__ __forceinline__ void kstep(const i32x4& w, float s, XS& a,
                                             const char* nxp,
                                             f32x4& c0, f32x4& c1, f32x4& c2, f32x4& c3) {
    short8 b;
    #pragma unroll
    for (int t = 0; t < 4; ++t) {
        int v = w[t];
        b[2 * t]     = bf(((float)(v & 0xF)        - 8.0f) * s);  // even k
        b[2 * t + 1] = bf(((float)((v >> 4) & 0xF) - 8.0f) * s);  // odd k
    }
    c0 = __builtin_amdgcn_mfma_f32_16x16x32_bf16(a.x0, b, c0, 0, 0, 0);
    c1 = __builtin_amdgcn_mfma_f32_16x16x32_bf16(a.x1, b, c1, 0, 0, 0);
    c2 = __builtin_amdgcn_mfma_f32_16x16x32_bf16(a.x2, b, c2, 0, 0, 0);
    c3 = __builtin_amdgcn_mfma_f32_16x16x32_bf16(a.x3, b, c3, 0, 0, 0);
    a = load_xs(nxp);
}

// One 128-k group: 4 ksteps; xg = next group's x base (this lane).
static __device__ __forceinline__ void group(const WGrp& p,
                                             XS& a0, XS& a1, XS& a2, XS& a3,
                                             const char* xg,
                                             f32x4& c0, f32x4& c1, f32x4& c2, f32x4& c3) {
    kstep(p.w0, p.s, a0, xg,         c0, c1, c2, c3);
    kstep(p.w1, p.s, a1, xg + 4096,  c0, c1, c2, c3);
    kstep(p.w2, p.s, a2, xg + 8192,  c0, c1, c2, c3);
    kstep(p.w3, p.s, a3, xg + 12288, c0, c1, c2, c3);
}

// x fp32 [64][K] -> bf16 in A-fragment order: xf[g][st][mt][lane][8]
__global__ __launch_bounds__(256)
void xpack_kernel(const float* __restrict__ x, unsigned short* __restrict__ xf, int K) {
    int c    = blockIdx.x * 256 + threadIdx.x;     // one 16 B chunk per thread
    int g    = c >> 10;
    int st   = (c >> 8) & 3;
    int mt   = (c >> 6) & 3;
    int lane = c & 63;
    int quad = lane >> 4, l15 = lane & 15;
    const float* p = x + (size_t)(l15 + mt * 16) * K + g * 128 + st * 32 + quad * 8;
    f32x4 lo = *(const f32x4*)p;
    f32x4 hi = *(const f32x4*)(p + 4);
    short8 r = { bf(lo[0]), bf(lo[1]), bf(lo[2]), bf(lo[3]),
                 bf(hi[0]), bf(hi[1]), bf(hi[2]), bf(hi[3]) };
    *(short8*)(xf + (size_t)c * 8) = r;
}

__global__ __launch_bounds__(256, 2)
void int4mm_kernel(const unsigned short* __restrict__ xf,  // bf16 frag-ordered x
                   const int*   __restrict__ wp,           // [N][K/2]
                   const float* __restrict__ sc,           // [N][K/128]
                   const float* __restrict__ bias,         // [N]
                   float*       __restrict__ out,          // [64][N]
                   int K, int N)
{
    const int lane = threadIdx.x & 63;
    const int wave = threadIdx.x >> 6;
    const int quad = lane >> 4;
    const int l15  = lane & 15;
    const int n    = (blockIdx.x * 4 + wave) * 16 + l15;   // this lane's N column
    const int Kh   = K >> 1;
    const int ng   = K / 128;                      // 64 groups (even)

    const int*   wrow = wp + (size_t)n * Kh + quad * 4;
    const float* srow = sc + (size_t)n * ng;
    const char*  xb   = (const char*)xf + lane * 16;   // this lane's frag base

    f32x4 acc0 = {0.f, 0.f, 0.f, 0.f};
    f32x4 acc1 = {0.f, 0.f, 0.f, 0.f};
    f32x4 acc2 = {0.f, 0.f, 0.f, 0.f};
    f32x4 acc3 = {0.f, 0.f, 0.f, 0.f};

    // Prologue: weights 2 groups deep, x window 4 ksteps deep (= group 0).
    WGrp p0 = load_grp(wrow, srow, 0);
    WGrp p1 = load_grp(wrow, srow, 1);
    XS a0 = load_xs(xb);
    XS a1 = load_xs(xb + 4096);
    XS a2 = load_xs(xb + 8192);
    XS a3 = load_xs(xb + 12288);

    #pragma unroll 1
    for (int g = 0; g < ng; g += 2) {
        const int r0 = (g + 2 < ng) ? g + 2 : ng - 1;   // clamped tail reloads
        const int r1 = (g + 3 < ng) ? g + 3 : ng - 1;   // (redundant, in-bounds)
        const int x0g = (g + 1 < ng) ? g + 1 : ng - 1;
        const int x1g = (g + 2 < ng) ? g + 2 : ng - 1;
        {
            WGrp t = load_grp(wrow, srow, r0);
            group(p0, a0, a1, a2, a3, xb + (size_t)x0g * 16384,
                  acc0, acc1, acc2, acc3);
            p0 = t;
        }
        {
            WGrp t = load_grp(wrow, srow, r1);
            group(p1, a0, a1, a2, a3, xb + (size_t)x1g * 16384,
                  acc0, acc1, acc2, acc3);
            p1 = t;
        }
    }

    // Epilogue. C/D layout (m89-verified): col = lane&15 (= n), row = quad*4 + reg.
    const float bv = bias[n];
    float* orow = out + (size_t)(quad * 4) * N + n;
    #pragma unroll
    for (int r = 0; r < 4; ++r) {
        orow[(size_t)(r)      * N] = acc0[r] + bv;
        orow[(size_t)(r + 16) * N] = acc1[r] + bv;
        orow[(size_t)(r + 32) * N] = acc2[r] + bv;
        orow[(size_t)(r + 48) * N] = acc3[r] + bv;
    }
}

extern "C" void kernel_launch(void* const* d_in, const int* in_sizes, int n_in,
                              void* d_out, int out_size, void* d_ws, size_t ws_size,
                              hipStream_t stream)
{
    const float* x    = (const float*)d_in[0];
    const int*   wp   = (const int*)d_in[1];
    const float* sc   = (const float*)d_in[2];
    const float* bias = (const float*)d_in[3];
    float*       out  = (float*)d_out;

    const int N  = in_sizes[3];                       // 28672
    const long long Kh = (long long)in_sizes[1] / N;  // 4096
    const int K  = (int)(2 * Kh);                     // 8192

    unsigned short* xf = (unsigned short*)d_ws;       // 1 MB frag-ordered bf16 x

    const int chunks = (K / 128) * 1024;              // 65536 x 16 B = 1 MB
    xpack_kernel<<<chunks / 256, 256, 0, stream>>>(x, xf, K);
    int4mm_kernel<<<N / 64, 256, 0, stream>>>(xf, wp, sc, bias, out, K, N);
}

// Round 6
// 169.170 us; speedup vs baseline: 1.7808x; 1.7808x over previous
//
#include <hip/hip_runtime.h>
#include <stdint.h>

// int4 grouped-quant GEMM: out[64][28672] = x[64][8192] . W^T + bias
// W packed [N][K/2] int32, one byte/int32 = 2 nibbles (low = even k), zp = 8,
// per-128-k scales. fp16 ref -> harness gives x/scales/bias/out as FP32.
// HBM-bound on the 470 MB weight stream (~75 us @ 6.3 TB/s achievable).
// Round-6: round-4 structure (xpack to A-frag order + global_load_lds staging,
// LDS double-buffer, per-group barrier) + SPLIT-K x4 for occupancy: 1792 WGs
// (~5 resident blocks/CU) so other blocks' waves cover each barrier's
// vmcnt(0) drain. Partials in d_ws, fixed-order reduce (+bias) kernel.

typedef __attribute__((ext_vector_type(8))) short short8;  // MFMA bf16 A/B frag
typedef __attribute__((ext_vector_type(4))) float f32x4;   // MFMA C/D frag
typedef __attribute__((ext_vector_type(4))) int   i32x4;

struct WGrp { i32x4 w0, w1, w2, w3; float s; };  // one 128-k weight group / lane

static __device__ __forceinline__ short bf(float f) {
    return __builtin_bit_cast(short, (__bf16)f);   // HW v_cvt, RNE
}

// async global->LDS, 16 B per lane. LDS dest = wave-uniform base + lane*16 (HW).
static __device__ __forceinline__ void gload_lds16(const void* gp, void* lp) {
    __builtin_amdgcn_global_load_lds(
        (const __attribute__((address_space(1))) unsigned int*)gp,
        (__attribute__((address_space(3))) unsigned int*)lp, 16, 0, 0);
}

// One 128-k weight group: 16 int32/lane, nontemporal (streamed once).
static __device__ __forceinline__ WGrp load_grp(const int* __restrict__ wrow,
                                                const float* __restrict__ srow, int g) {
    WGrp r;
    const i32x4* p = (const i32x4*)(wrow + g * 64);
    r.w0 = __builtin_nontemporal_load(p);
    r.w1 = __builtin_nontemporal_load(p + 4);
    r.w2 = __builtin_nontemporal_load(p + 8);
    r.w3 = __builtin_nontemporal_load(p + 12);
    r.s  = srow[g];
    return r;
}

// One 32-k MFMA step, 4 m-tiles. A-frags from LDS at ab + mt*1024 + lane*16.
static __device__ __forceinline__ void kstep(const i32x4& w, float s,
                                             const char* ab, int lane,
                                             f32x4& a0, f32x4& a1, f32x4& a2, f32x4& a3) {
    short8 b;
    #pragma unroll
    for (int t = 0; t < 4; ++t) {
        int v = w[t];
        b[2 * t]     = bf(((float)(v & 0xF)        - 8.0f) * s);  // even k
        b[2 * t + 1] = bf(((float)((v >> 4) & 0xF) - 8.0f) * s);  // odd k
    }
    short8 x0 = *(const short8*)(ab +    0 + lane * 16);
    short8 x1 = *(const short8*)(ab + 1024 + lane * 16);
    short8 x2 = *(const short8*)(ab + 2048 + lane * 16);
    short8 x3 = *(const short8*)(ab + 3072 + lane * 16);
    a0 = __builtin_amdgcn_mfma_f32_16x16x32_bf16(x0, b, a0, 0, 0, 0);
    a1 = __builtin_amdgcn_mfma_f32_16x16x32_bf16(x1, b, a1, 0, 0, 0);
    a2 = __builtin_amdgcn_mfma_f32_16x16x32_bf16(x2, b, a2, 0, 0, 0);
    a3 = __builtin_amdgcn_mfma_f32_16x16x32_bf16(x3, b, a3, 0, 0, 0);
}

static __device__ __forceinline__ void compute_grp(const WGrp& p, const char* buf, int lane,
                                                   f32x4& a0, f32x4& a1, f32x4& a2, f32x4& a3) {
    kstep(p.w0, p.s, buf,         lane, a0, a1, a2, a3);
    kstep(p.w1, p.s, buf +  4096, lane, a0, a1, a2, a3);
    kstep(p.w2, p.s, buf +  8192, lane, a0, a1, a2, a3);
    kstep(p.w3, p.s, buf + 12288, lane, a0, a1, a2, a3);
}

// Stage (relative) group g (16 KB frag-ordered bf16) into LDS. Wave copies 4 KB.
static __device__ __forceinline__ void stage_grp(const unsigned short* __restrict__ xsrc,
                                                 int g, char* buf, int wave, int lane) {
    const char* src = (const char*)xsrc + (size_t)g * 16384 + wave * 4096 + lane * 16;
    char* dst = buf + wave * 4096;                 // wave-uniform; HW adds lane*16
    #pragma unroll
    for (int j = 0; j < 4; ++j)
        gload_lds16(src + j * 1024, dst + j * 1024);
}

// x fp32 [64][K] -> bf16 in A-fragment order: xf[g][st][mt][lane][8]
__global__ __launch_bounds__(256)
void xpack_kernel(const float* __restrict__ x, unsigned short* __restrict__ xf, int K) {
    int c    = blockIdx.x * 256 + threadIdx.x;     // one 16 B chunk per thread
    int g    = c >> 10;
    int st   = (c >> 8) & 3;
    int mt   = (c >> 6) & 3;
    int lane = c & 63;
    int quad = lane >> 4, l15 = lane & 15;
    const float* p = x + (size_t)(l15 + mt * 16) * K + g * 128 + st * 32 + quad * 8;
    f32x4 lo = *(const f32x4*)p;
    f32x4 hi = *(const f32x4*)(p + 4);
    short8 r = { bf(lo[0]), bf(lo[1]), bf(lo[2]), bf(lo[3]),
                 bf(hi[0]), bf(hi[1]), bf(hi[2]), bf(hi[3]) };
    *(short8*)(xf + (size_t)c * 8) = r;
}

// bias == nullptr: write fp32 partial to dst + ks*64*N (split-K path).
// bias != nullptr: single-split, add bias, write final.
__global__ __launch_bounds__(256)
void int4mm_kernel(const unsigned short* __restrict__ xf,  // bf16 frag-ordered x
                   const int*   __restrict__ wp,           // [N][K/2]
                   const float* __restrict__ sc,           // [N][K/128]
                   const float* __restrict__ bias,         // [N] or nullptr
                   float*       __restrict__ dst,
                   int K, int N, int ksbits, int gps)      // gps = groups per split
{
    __shared__ i32x4 ldsq[2048];                   // 2 x 16 KB double buffer
    char* ldsA = (char*)ldsq;
    char* ldsB = ldsA + 16384;

    const int bid   = blockIdx.x;
    const int ks    = bid & ((1 << ksbits) - 1);
    const int ntile = bid >> ksbits;
    const int lane  = threadIdx.x & 63;
    const int wave  = threadIdx.x >> 6;
    const int quad  = lane >> 4;
    const int l15   = lane & 15;
    const int n     = (ntile * 4 + wave) * 16 + l15;   // this lane's N column
    const int Kh    = K >> 1;
    const int ng    = K / 128;
    const int g0    = ks * gps;

    const int*   wrow = wp + (size_t)n * Kh + quad * 4 + (size_t)g0 * 64;
    const float* srow = sc + (size_t)n * ng + g0;
    const unsigned short* xsrc = xf + (size_t)g0 * 8192;   // 16384 B = 8192 ushort

    f32x4 acc0 = {0.f, 0.f, 0.f, 0.f};
    f32x4 acc1 = {0.f, 0.f, 0.f, 0.f};
    f32x4 acc2 = {0.f, 0.f, 0.f, 0.f};
    f32x4 acc3 = {0.f, 0.f, 0.f, 0.f};

    // Prologue: weights 2 groups deep (relative indices), x group 0 staged.
    WGrp p0 = load_grp(wrow, srow, 0);
    stage_grp(xsrc, 0, ldsA, wave, lane);
    WGrp p1 = load_grp(wrow, srow, (1 < gps) ? 1 : 0);
    __syncthreads();

    #pragma unroll 1
    for (int i = 0; i < gps; i += 2) {
        {   // phase A: compute group i from ldsA
            WGrp t = load_grp(wrow, srow, (i + 2 < gps) ? i + 2 : gps - 1);
            if (i + 1 < gps) stage_grp(xsrc, i + 1, ldsB, wave, lane);
            compute_grp(p0, ldsA, lane, acc0, acc1, acc2, acc3);
            p0 = t;
            __syncthreads();
        }
        {   // phase B: compute group i+1 from ldsB
            WGrp t = load_grp(wrow, srow, (i + 3 < gps) ? i + 3 : gps - 1);
            if (i + 2 < gps) stage_grp(xsrc, i + 2, ldsA, wave, lane);
            if (i + 1 < gps)
                compute_grp(p1, ldsB, lane, acc0, acc1, acc2, acc3);
            p1 = t;
            __syncthreads();
        }
    }

    // Epilogue. C/D layout (m89-verified): col = lane&15 (= n), row = quad*4 + reg.
    const float bv = bias ? bias[n] : 0.0f;
    float* orow = dst + (size_t)ks * 64 * N + (size_t)(quad * 4) * N + n;
    #pragma unroll
    for (int r = 0; r < 4; ++r) {
        orow[(size_t)(r)      * N] = acc0[r] + bv;
        orow[(size_t)(r + 16) * N] = acc1[r] + bv;
        orow[(size_t)(r + 32) * N] = acc2[r] + bv;
        orow[(size_t)(r + 48) * N] = acc3[r] + bv;
    }
}

// out[i] = sum_{ks<4} pbuf[ks][i] + bias[i % N], fixed order (deterministic).
__global__ __launch_bounds__(256)
void reduce_kernel(const float* __restrict__ pbuf, const float* __restrict__ bias,
                   float* __restrict__ out, int N, int total) {
    int i = (blockIdx.x * 256 + threadIdx.x) * 4;
    if (i >= total) return;
    f32x4 s0 = *(const f32x4*)(pbuf + i);
    f32x4 s1 = *(const f32x4*)(pbuf + (size_t)total + i);
    f32x4 s2 = *(const f32x4*)(pbuf + 2 * (size_t)total + i);
    f32x4 s3 = *(const f32x4*)(pbuf + 3 * (size_t)total + i);
    f32x4 b  = *(const f32x4*)(bias + (i % N));
    f32x4 r  = (s0 + s1) + (s2 + s3) + b;
    *(f32x4*)(out + i) = r;
}

extern "C" void kernel_launch(void* const* d_in, const int* in_sizes, int n_in,
                              void* d_out, int out_size, void* d_ws, size_t ws_size,
                              hipStream_t stream)
{
    const float* x    = (const float*)d_in[0];
    const int*   wp   = (const int*)d_in[1];
    const float* sc   = (const float*)d_in[2];
    const float* bias = (const float*)d_in[3];
    float*       out  = (float*)d_out;

    const int N  = in_sizes[3];                       // 28672
    const long long Kh = (long long)in_sizes[1] / N;  // 4096
    const int K  = (int)(2 * Kh);                     // 8192
    const int ng = K / 128;                           // 64

    unsigned short* xf = (unsigned short*)d_ws;       // 1 MB frag-ordered bf16 x
    const size_t xf_bytes = (size_t)ng * 16384;
    const int    total    = 64 * N;
    const size_t need     = xf_bytes + 4ull * total * 4ull;

    const int chunks = ng * 1024;                     // 16 B chunks of xf
    xpack_kernel<<<chunks / 256, 256, 0, stream>>>(x, xf, K);

    if (ws_size >= need && (ng & 7) == 0) {
        // split-K x4: 1792 WGs, partials in ws, then reduce.
        float* pbuf = (float*)((char*)d_ws + xf_bytes);
        int4mm_kernel<<<(N / 64) * 4, 256, 0, stream>>>(xf, wp, sc, nullptr, pbuf,
                                                        K, N, 2, ng / 4);
        reduce_kernel<<<(total / 4 + 255) / 256, 256, 0, stream>>>(pbuf, bias, out,
                                                                   N, total);
    } else {
        // fallback: single split (round-4 path)
        int4mm_kernel<<<N / 64, 256, 0, stream>>>(xf, wp, sc, bias, out,
                                                  K, N, 0, ng);
    }
}

// Round 7
// 136.729 us; speedup vs baseline: 2.2034x; 1.2373x over previous
//
#include <hip/hip_runtime.h>
#include <stdint.h>

// int4 grouped-quant GEMM: out[64][28672] = x[64][8192] . W^T + bias
// W packed [N][K/2] int32, one byte/int32 = 2 nibbles (low = even k), zp = 8,
// per-128-k scales. fp16 ref -> harness gives x/scales/bias/out as FP32.
// Round-7: weight loads were request-rate-bound (64 lanes x 16B at 16KB stride
// = 64 line-requests/instr; ~458K req/CU ~ 168 us). Fix: stage weights
// global->LDS coalesced (global_load_lds, pre-swizzled per-lane sources,
// swizzled conflict-free ds_read_b128), x staged as before, scales transposed
// to [g][N] by a pre-pass. HBM-bound target: 470 MB @ ~6 TB/s ~ 80 us.

typedef __attribute__((ext_vector_type(8))) short short8;  // MFMA bf16 A/B frag
typedef __attribute__((ext_vector_type(4))) float f32x4;   // MFMA C/D frag
typedef __attribute__((ext_vector_type(4))) int   i32x4;

static __device__ __forceinline__ short bf(float f) {
    return __builtin_bit_cast(short, (__bf16)f);   // HW v_cvt, RNE
}

// async global->LDS, 16 B/lane. LDS dest = wave-uniform base + lane*16 (HW);
// global source is PER-LANE -> swizzled layouts via pre-swizzled source (m173).
static __device__ __forceinline__ void gload_lds16(const void* gp, void* lp) {
    __builtin_amdgcn_global_load_lds(
        (const __attribute__((address_space(1))) unsigned int*)gp,
        (__attribute__((address_space(3))) unsigned int*)lp, 16, 0, 0);
}

// One 32-k MFMA step, 4 m-tiles. A-frags from LDS at xb + mt*1024 + lane*16.
static __device__ __forceinline__ void kstep(const i32x4& w, float s,
                                             const char* xb, int lane,
                                             f32x4& a0, f32x4& a1, f32x4& a2, f32x4& a3) {
    short8 b;
    #pragma unroll
    for (int t = 0; t < 4; ++t) {
        int v = w[t];
        b[2 * t]     = bf(((float)(v & 0xF)        - 8.0f) * s);  // even k
        b[2 * t + 1] = bf(((float)((v >> 4) & 0xF) - 8.0f) * s);  // odd k
    }
    short8 x0 = *(const short8*)(xb +    0 + lane * 16);
    short8 x1 = *(const short8*)(xb + 1024 + lane * 16);
    short8 x2 = *(const short8*)(xb + 2048 + lane * 16);
    short8 x3 = *(const short8*)(xb + 3072 + lane * 16);
    a0 = __builtin_amdgcn_mfma_f32_16x16x32_bf16(x0, b, a0, 0, 0, 0);
    a1 = __builtin_amdgcn_mfma_f32_16x16x32_bf16(x1, b, a1, 0, 0, 0);
    a2 = __builtin_amdgcn_mfma_f32_16x16x32_bf16(x2, b, a2, 0, 0, 0);
    a3 = __builtin_amdgcn_mfma_f32_16x16x32_bf16(x3, b, a3, 0, 0, 0);
}

// x fp32 [64][K] -> bf16 in A-fragment order: xf[g][st][mt][lane][8]
__global__ __launch_bounds__(256)
void xpack_kernel(const float* __restrict__ x, unsigned short* __restrict__ xf, int K) {
    int c    = blockIdx.x * 256 + threadIdx.x;     // one 16 B chunk per thread
    int g    = c >> 10;
    int st   = (c >> 8) & 3;
    int mt   = (c >> 6) & 3;
    int lane = c & 63;
    int quad = lane >> 4, l15 = lane & 15;
    const float* p = x + (size_t)(l15 + mt * 16) * K + g * 128 + st * 32 + quad * 8;
    f32x4 lo = *(const f32x4*)p;
    f32x4 hi = *(const f32x4*)(p + 4);
    short8 r = { bf(lo[0]), bf(lo[1]), bf(lo[2]), bf(lo[3]),
                 bf(hi[0]), bf(hi[1]), bf(hi[2]), bf(hi[3]) };
    *(short8*)(xf + (size_t)c * 8) = r;
}

// scales [N][ng] -> [ng][N] (write-coalesced)
__global__ __launch_bounds__(256)
void strans_kernel(const float* __restrict__ sc, float* __restrict__ sct, int N, int ng) {
    int n = blockIdx.x * 256 + threadIdx.x;
    int g = blockIdx.y;
    sct[(size_t)g * N + n] = sc[(size_t)n * ng + g];
}

__global__ __launch_bounds__(256)
void int4mm_kernel(const unsigned short* __restrict__ xf,  // bf16 frag-ordered x
                   const int*   __restrict__ wp,           // [N][K/2]
                   const float* __restrict__ sc,           // [N][ng] (fallback)
                   const float* __restrict__ sct,          // [ng][N] or nullptr
                   const float* __restrict__ bias,         // [N]
                   float*       __restrict__ out,          // [64][N]
                   int K, int N)
{
    __shared__ i32x4 ldsq[4096];                   // 64 KB: Wdbuf 32K | Xdbuf 32K
    char* ldsW = (char*)ldsq;
    char* ldsX = ldsW + 32768;

    const int lane = threadIdx.x & 63;
    const int wave = threadIdx.x >> 6;
    const int quad = lane >> 4;
    const int l15  = lane & 15;
    const int blk64 = blockIdx.x * 64;
    const int n    = blk64 + wave * 16 + l15;      // this lane's N column
    const int ng   = K / 128;                      // 64 groups

    const char* wp8 = (const char*)wp;             // W row n = 16384 B; group = 256 B

    // --- weight stage sources (per lane, g-independent part) ---------------
    // Stage instr j of wave w writes LDS slots S = (w*4+j)*64 + lane; slot
    // (c = S>>4, s = S&15) must hold global chunk (s ^ (c&15)) of col c:
    // col c = w*16 + j*4 + quad, chunk = l15 ^ (j*4 + quad).  (16B chunks)
    unsigned woff[4];
    #pragma unroll
    for (int j = 0; j < 4; ++j) {
        int cloc  = wave * 16 + j * 4 + quad;               // staged local col
        int chunk = l15 ^ (j * 4 + quad);
        woff[j] = ((unsigned)(blk64 + cloc) << 14) + ((unsigned)chunk << 4);
    }

    // --- swizzled weight ds_read offsets (per lane, g-independent) ---------
    // reader col c = wave*16 + l15; chunk (quad + 4t) lives at slot
    // ((quad+4t) ^ (c&15)) = ((quad+4t) ^ l15)  -> conflict-free (8 beats).
    const int cbase = (wave * 16 + l15) * 256;
    const int rd0 = cbase + (((quad + 0)  ^ l15) << 4);
    const int rd1 = cbase + (((quad + 4)  ^ l15) << 4);
    const int rd2 = cbase + (((quad + 8)  ^ l15) << 4);
    const int rd3 = cbase + (((quad + 12) ^ l15) << 4);

    f32x4 acc0 = {0.f, 0.f, 0.f, 0.f};
    f32x4 acc1 = {0.f, 0.f, 0.f, 0.f};
    f32x4 acc2 = {0.f, 0.f, 0.f, 0.f};
    f32x4 acc3 = {0.f, 0.f, 0.f, 0.f};

    // Prologue: stage group 0 into buffer 0 (weights + x), prefetch scale 0.
    #pragma unroll
    for (int j = 0; j < 4; ++j)
        gload_lds16(wp8 + woff[j], ldsW + (wave * 4 + j) * 1024);
    {
        const char* xs = (const char*)xf + wave * 4096 + lane * 16;
        char* xd = ldsX + wave * 4096;
        #pragma unroll
        for (int j = 0; j < 4; ++j)
            gload_lds16(xs + j * 1024, xd + j * 1024);
    }
    float s_cur = sct ? sct[n] : sc[(size_t)n * ng];
    __syncthreads();

    #pragma unroll 1
    for (int g = 0; g < ng; ++g) {
        const int p  = g & 1;
        const int gn = (g + 1 < ng) ? g + 1 : ng - 1;   // clamped tail restage

        // stage group g+1 into the other buffer (issue FIRST: fills HBM queue)
        {
            char* bw = ldsW + (p ^ 1) * 16384;
            #pragma unroll
            for (int j = 0; j < 4; ++j)
                gload_lds16(wp8 + woff[j] + (size_t)gn * 256,
                            bw + (wave * 4 + j) * 1024);
            const char* xs = (const char*)xf + (size_t)gn * 16384
                           + wave * 4096 + lane * 16;
            char* xd = ldsX + (p ^ 1) * 16384 + wave * 4096;
            #pragma unroll
            for (int j = 0; j < 4; ++j)
                gload_lds16(xs + j * 1024, xd + j * 1024);
        }

        const float s = s_cur;
        s_cur = sct ? sct[(size_t)gn * N + n] : sc[(size_t)n * ng + gn];

        // weight fragments from LDS (swizzled, conflict-free)
        const char* wb = ldsW + p * 16384;
        i32x4 v0 = *(const i32x4*)(wb + rd0);
        i32x4 v1 = *(const i32x4*)(wb + rd1);
        i32x4 v2 = *(const i32x4*)(wb + rd2);
        i32x4 v3 = *(const i32x4*)(wb + rd3);

        const char* xb = ldsX + p * 16384;
        kstep(v0, s, xb,         lane, acc0, acc1, acc2, acc3);
        kstep(v1, s, xb +  4096, lane, acc0, acc1, acc2, acc3);
        kstep(v2, s, xb +  8192, lane, acc0, acc1, acc2, acc3);
        kstep(v3, s, xb + 12288, lane, acc0, acc1, acc2, acc3);

        __syncthreads();
    }

    // Epilogue. C/D layout (m89-verified): col = lane&15 (= n), row = quad*4 + reg.
    const float bv = bias[n];
    float* orow = out + (size_t)(quad * 4) * N + n;
    #pragma unroll
    for (int r = 0; r < 4; ++r) {
        orow[(size_t)(r)      * N] = acc0[r] + bv;
        orow[(size_t)(r + 16) * N] = acc1[r] + bv;
        orow[(size_t)(r + 32) * N] = acc2[r] + bv;
        orow[(size_t)(r + 48) * N] = acc3[r] + bv;
    }
}

extern "C" void kernel_launch(void* const* d_in, const int* in_sizes, int n_in,
                              void* d_out, int out_size, void* d_ws, size_t ws_size,
                              hipStream_t stream)
{
    const float* x    = (const float*)d_in[0];
    const int*   wp   = (const int*)d_in[1];
    const float* sc   = (const float*)d_in[2];
    const float* bias = (const float*)d_in[3];
    float*       out  = (float*)d_out;

    const int N  = in_sizes[3];                       // 28672
    const long long Kh = (long long)in_sizes[1] / N;  // 4096
    const int K  = (int)(2 * Kh);                     // 8192
    const int ng = K / 128;                           // 64

    unsigned short* xf = (unsigned short*)d_ws;       // 1 MB frag-ordered bf16 x
    const size_t xf_bytes  = (size_t)ng * 16384;
    const size_t sct_bytes = (size_t)ng * N * 4;
    float* sct = nullptr;

    xpack_kernel<<<(ng * 1024) / 256, 256, 0, stream>>>(x, xf, K);
    if (ws_size >= xf_bytes + sct_bytes && (N & 255) == 0) {
        sct = (float*)((char*)d_ws + xf_bytes);
        strans_kernel<<<dim3(N / 256, ng), 256, 0, stream>>>(sc, sct, N, ng);
    }
    int4mm_kernel<<<N / 64, 256, 0, stream>>>(xf, wp, sc, sct, bias, out, K, N);
}

// Round 8
// 135.599 us; speedup vs baseline: 2.2217x; 1.0083x over previous
//
#include <hip/hip_runtime.h>
#include <stdint.h>

// int4 grouped-quant GEMM: out[64][28672] = x[64][8192] . W^T + bias
// W packed [N][K/2] int32, one byte/int32 = 2 nibbles (low = even k), zp = 8,
// per-128-k scales. fp16 ref -> harness gives x/scales/bias/out as FP32.
// Round-8: round-7 structure (coalesced W+X staging via global_load_lds,
// swizzled conflict-free ds_read) but the per-group __syncthreads (vmcnt(0)
// drain, m97 stall) is replaced by T4 counted-vmcnt + raw barriers: exactly
// 9 VMEM/iter (8 stage + 1 scale), manual s_waitcnt vmcnt(9) -> the g+1
// prefetch stays in flight across both barriers. HBM target ~75-90 us.

typedef __attribute__((ext_vector_type(8))) short short8;  // MFMA bf16 A/B frag
typedef __attribute__((ext_vector_type(4))) float f32x4;   // MFMA C/D frag
typedef __attribute__((ext_vector_type(4))) int   i32x4;

static __device__ __forceinline__ short bf(float f) {
    return __builtin_bit_cast(short, (__bf16)f);   // HW v_cvt, RNE
}

// async global->LDS, 16 B/lane. LDS dest = wave-uniform base + lane*16 (HW);
// global source is PER-LANE -> swizzled layouts via pre-swizzled source (m173).
static __device__ __forceinline__ void gload_lds16(const void* gp, void* lp) {
    __builtin_amdgcn_global_load_lds(
        (const __attribute__((address_space(1))) unsigned int*)gp,
        (__attribute__((address_space(3))) unsigned int*)lp, 16, 0, 0);
}

// One 32-k MFMA step, 4 m-tiles. A-frags from LDS at xb + mt*1024 + lane*16.
static __device__ __forceinline__ void kstep(const i32x4& w, float s,
                                             const char* xb, int lane,
                                             f32x4& a0, f32x4& a1, f32x4& a2, f32x4& a3) {
    short8 b;
    #pragma unroll
    for (int t = 0; t < 4; ++t) {
        int v = w[t];
        b[2 * t]     = bf(((float)(v & 0xF)        - 8.0f) * s);  // even k
        b[2 * t + 1] = bf(((float)((v >> 4) & 0xF) - 8.0f) * s);  // odd k
    }
    short8 x0 = *(const short8*)(xb +    0 + lane * 16);
    short8 x1 = *(const short8*)(xb + 1024 + lane * 16);
    short8 x2 = *(const short8*)(xb + 2048 + lane * 16);
    short8 x3 = *(const short8*)(xb + 3072 + lane * 16);
    a0 = __builtin_amdgcn_mfma_f32_16x16x32_bf16(x0, b, a0, 0, 0, 0);
    a1 = __builtin_amdgcn_mfma_f32_16x16x32_bf16(x1, b, a1, 0, 0, 0);
    a2 = __builtin_amdgcn_mfma_f32_16x16x32_bf16(x2, b, a2, 0, 0, 0);
    a3 = __builtin_amdgcn_mfma_f32_16x16x32_bf16(x3, b, a3, 0, 0, 0);
}

// x fp32 [64][K] -> bf16 in A-fragment order: xf[g][st][mt][lane][8]
__global__ __launch_bounds__(256)
void xpack_kernel(const float* __restrict__ x, unsigned short* __restrict__ xf, int K) {
    int c    = blockIdx.x * 256 + threadIdx.x;     // one 16 B chunk per thread
    int g    = c >> 10;
    int st   = (c >> 8) & 3;
    int mt   = (c >> 6) & 3;
    int lane = c & 63;
    int quad = lane >> 4, l15 = lane & 15;
    const float* p = x + (size_t)(l15 + mt * 16) * K + g * 128 + st * 32 + quad * 8;
    f32x4 lo = *(const f32x4*)p;
    f32x4 hi = *(const f32x4*)(p + 4);
    short8 r = { bf(lo[0]), bf(lo[1]), bf(lo[2]), bf(lo[3]),
                 bf(hi[0]), bf(hi[1]), bf(hi[2]), bf(hi[3]) };
    *(short8*)(xf + (size_t)c * 8) = r;
}

// scales [N][ng] -> [ng][N] (write-coalesced)
__global__ __launch_bounds__(256)
void strans_kernel(const float* __restrict__ sc, float* __restrict__ sct, int N, int ng) {
    int n = blockIdx.x * 256 + threadIdx.x;
    int g = blockIdx.y;
    sct[(size_t)g * N + n] = sc[(size_t)n * ng + g];
}

__global__ __launch_bounds__(256)
void int4mm_kernel(const unsigned short* __restrict__ xf,  // bf16 frag-ordered x
                   const int*   __restrict__ wp,           // [N][K/2]
                   const float* __restrict__ sc,           // [N][ng] (fallback)
                   const float* __restrict__ sct,          // [ng][N] or nullptr
                   const float* __restrict__ bias,         // [N]
                   float*       __restrict__ out,          // [64][N]
                   int K, int N)
{
    __shared__ i32x4 ldsq[4096];                   // 64 KB: Wdbuf 32K | Xdbuf 32K
    char* ldsW = (char*)ldsq;
    char* ldsX = ldsW + 32768;

    const int lane = threadIdx.x & 63;
    const int wave = threadIdx.x >> 6;
    const int quad = lane >> 4;
    const int l15  = lane & 15;
    const int blk64 = blockIdx.x * 64;
    const int n    = blk64 + wave * 16 + l15;      // this lane's N column
    const int ng   = K / 128;                      // 64 groups

    const char* wp8 = (const char*)wp;             // W row n = 16384 B; group = 256 B

    // Stage sources (per lane): stage instr j of wave w writes LDS slots
    // S = (w*4+j)*64 + lane; slot (c=S>>4, s=S&15) holds global chunk
    // (s ^ (c&15)) of col c -> col = w*16+j*4+quad, chunk = l15 ^ (j*4+quad).
    unsigned woff[4];
    #pragma unroll
    for (int j = 0; j < 4; ++j) {
        int cloc  = wave * 16 + j * 4 + quad;
        int chunk = l15 ^ (j * 4 + quad);
        woff[j] = ((unsigned)(blk64 + cloc) << 14) + ((unsigned)chunk << 4);
    }

    // Swizzled W ds_read offsets: reader col c = wave*16+l15; chunk (quad+4t)
    // lives at slot ((quad+4t) ^ l15) -> conflict-free (8 beats/instr).
    const int cbase = (wave * 16 + l15) * 256;
    const int rd0 = cbase + (((quad + 0)  ^ l15) << 4);
    const int rd1 = cbase + (((quad + 4)  ^ l15) << 4);
    const int rd2 = cbase + (((quad + 8)  ^ l15) << 4);
    const int rd3 = cbase + (((quad + 12) ^ l15) << 4);

    f32x4 acc0 = {0.f, 0.f, 0.f, 0.f};
    f32x4 acc1 = {0.f, 0.f, 0.f, 0.f};
    f32x4 acc2 = {0.f, 0.f, 0.f, 0.f};
    f32x4 acc3 = {0.f, 0.f, 0.f, 0.f};

    // Prologue: stage group 0 into buffer 0 (8 VMEM) + scale 0 (1 VMEM).
    #pragma unroll
    for (int j = 0; j < 4; ++j)
        gload_lds16(wp8 + woff[j], ldsW + (wave * 4 + j) * 1024);
    {
        const char* xs = (const char*)xf + wave * 4096 + lane * 16;
        char* xd = ldsX + wave * 4096;
        #pragma unroll
        for (int j = 0; j < 4; ++j)
            gload_lds16(xs + j * 1024, xd + j * 1024);
    }
    float s_cur = sct ? sct[n] : sc[(size_t)n * ng];

    // Main loop: 2 raw barriers/group, vmcnt never drained to 0.
    // Per-iter VMEM = 8 stage + 1 scale = 9; vmcnt(9) at iter g leaves
    // {stage(g+1), scale(g+1)} in flight and guarantees stage(g)+scale(g) done.
    #pragma unroll 1
    for (int g = 0; g < ng; ++g) {
        const int p  = g & 1;
        const int gn = (g + 1 < ng) ? g + 1 : ng - 1;   // clamped tail restage

        __builtin_amdgcn_s_barrier();       // all waves done reading buf[p^1]

        {   // stage group g+1 into buf[p^1]
            char* bw = ldsW + (p ^ 1) * 16384;
            #pragma unroll
            for (int j = 0; j < 4; ++j)
                gload_lds16(wp8 + woff[j] + (size_t)gn * 256,
                            bw + (wave * 4 + j) * 1024);
            const char* xs = (const char*)xf + (size_t)gn * 16384
                           + wave * 4096 + lane * 16;
            char* xd = ldsX + (p ^ 1) * 16384 + wave * 4096;
            #pragma unroll
            for (int j = 0; j < 4; ++j)
                gload_lds16(xs + j * 1024, xd + j * 1024);
        }
        float s_nxt = sct ? sct[(size_t)gn * N + n] : sc[(size_t)n * ng + gn];

        asm volatile("s_waitcnt vmcnt(9)" ::: "memory");  // stage(g) complete (mine)
        __builtin_amdgcn_s_barrier();                     // ... for all waves

        const float s = s_cur;
        const char* wb = ldsW + p * 16384;
        i32x4 v0 = *(const i32x4*)(wb + rd0);
        i32x4 v1 = *(const i32x4*)(wb + rd1);
        i32x4 v2 = *(const i32x4*)(wb + rd2);
        i32x4 v3 = *(const i32x4*)(wb + rd3);

        const char* xb = ldsX + p * 16384;
        kstep(v0, s, xb,         lane, acc0, acc1, acc2, acc3);
        kstep(v1, s, xb +  4096, lane, acc0, acc1, acc2, acc3);
        kstep(v2, s, xb +  8192, lane, acc0, acc1, acc2, acc3);
        kstep(v3, s, xb + 12288, lane, acc0, acc1, acc2, acc3);

        s_cur = s_nxt;
    }

    // Epilogue. C/D layout (m89-verified): col = lane&15 (= n), row = quad*4 + reg.
    const float bv = bias[n];
    float* orow = out + (size_t)(quad * 4) * N + n;
    #pragma unroll
    for (int r = 0; r < 4; ++r) {
        orow[(size_t)(r)      * N] = acc0[r] + bv;
        orow[(size_t)(r + 16) * N] = acc1[r] + bv;
        orow[(size_t)(r + 32) * N] = acc2[r] + bv;
        orow[(size_t)(r + 48) * N] = acc3[r] + bv;
    }
}

extern "C" void kernel_launch(void* const* d_in, const int* in_sizes, int n_in,
                              void* d_out, int out_size, void* d_ws, size_t ws_size,
                              hipStream_t stream)
{
    const float* x    = (const float*)d_in[0];
    const int*   wp   = (const int*)d_in[1];
    const float* sc   = (const float*)d_in[2];
    const float* bias = (const float*)d_in[3];
    float*       out  = (float*)d_out;

    const int N  = in_sizes[3];                       // 28672
    const long long Kh = (long long)in_sizes[1] / N;  // 4096
    const int K  = (int)(2 * Kh);                     // 8192
    const int ng = K / 128;                           // 64

    unsigned short* xf = (unsigned short*)d_ws;       // 1 MB frag-ordered bf16 x
    const size_t xf_bytes  = (size_t)ng * 16384;
    const size_t sct_bytes = (size_t)ng * N * 4;
    float* sct = nullptr;

    xpack_kernel<<<(ng * 1024) / 256, 256, 0, stream>>>(x, xf, K);
    if (ws_size >= xf_bytes + sct_bytes && (N & 255) == 0) {
        sct = (float*)((char*)d_ws + xf_bytes);
        strans_kernel<<<dim3(N / 256, ng), 256, 0, stream>>>(sc, sct, N, ng);
    }
    int4mm_kernel<<<N / 64, 256, 0, stream>>>(xf, wp, sc, sct, bias, out, K, N);
}

// Round 9
// 135.175 us; speedup vs baseline: 2.2287x; 1.0031x over previous
//
#include <hip/hip_runtime.h>
#include <stdint.h>

// int4 grouped-quant GEMM: out[64][28672] = x[64][8192] . W^T + bias
// W packed [N][K/2] int32, one byte/int32 = 2 nibbles (low = even k), zp = 8,
// per-128-k scales. fp16 ref -> harness gives x/scales/bias/out as FP32.
// Round-9: TRUE distance-2 weight prefetch. vmcnt counts in issue order, so
// round-8's [W,X then wait] collapsed W to distance-1. Now: triple-buffer W,
// double-buffer X, per-iter issue [X(g+1), sc(g+1), W(g+2)], wait vmcnt(13)
// -> W(g+1) stays in flight across both barriers. Dequant switched to the
// fp16 0x6400-bias trick + mfma_f32_16x16x32_f16 (matches ref arithmetic:
// x/scales were fp16 originally, so f32->f16 is lossless).

typedef __attribute__((ext_vector_type(8))) short     short8;
typedef __attribute__((ext_vector_type(4))) float     f32x4;
typedef __attribute__((ext_vector_type(4))) int       i32x4;
typedef __attribute__((ext_vector_type(2))) _Float16  f16x2;
typedef __attribute__((ext_vector_type(8))) _Float16  f16x8;

// async global->LDS, 16 B/lane. LDS dest = wave-uniform base + lane*16 (HW);
// global source is PER-LANE -> swizzled layouts via pre-swizzled source (m173).
static __device__ __forceinline__ void gload_lds16(const void* gp, void* lp) {
    __builtin_amdgcn_global_load_lds(
        (const __attribute__((address_space(1))) unsigned int*)gp,
        (__attribute__((address_space(3))) unsigned int*)lp, 16, 0, 0);
}

// int4 pair -> fp16 pair: u = 0x6400|nib (fp16 1024+v, exact), (u-1032) exact
// in f16 (= v-8), then *s (single rounding — same as reference's fp16 mul).
static __device__ __forceinline__ f16x8 dequant(const i32x4& w, f16x2 s2) {
    const f16x2 c1032 = {(_Float16)1032.0f, (_Float16)1032.0f};
    union { unsigned u[4]; f16x8 v; } r;
    #pragma unroll
    for (int j = 0; j < 4; ++j) {
        unsigned v = (unsigned)w[j];
        unsigned u = ((v & 0xFu) | 0x64006400u) | ((v << 12) & 0xF0000u);
        f16x2 h = __builtin_bit_cast(f16x2, u);
        h = (h - c1032) * s2;
        r.u[j] = __builtin_bit_cast(unsigned, h);
    }
    return r.v;
}

// One 32-k MFMA step, 4 m-tiles. A-frags (fp16) from LDS at xb + mt*1024 + lane*16.
static __device__ __forceinline__ void kstep(const i32x4& w, f16x2 s2,
                                             const char* xb, int lane,
                                             f32x4& a0, f32x4& a1, f32x4& a2, f32x4& a3) {
    f16x8 b  = dequant(w, s2);
    f16x8 x0 = __builtin_bit_cast(f16x8, *(const short8*)(xb +    0 + lane * 16));
    f16x8 x1 = __builtin_bit_cast(f16x8, *(const short8*)(xb + 1024 + lane * 16));
    f16x8 x2 = __builtin_bit_cast(f16x8, *(const short8*)(xb + 2048 + lane * 16));
    f16x8 x3 = __builtin_bit_cast(f16x8, *(const short8*)(xb + 3072 + lane * 16));
    a0 = __builtin_amdgcn_mfma_f32_16x16x32_f16(x0, b, a0, 0, 0, 0);
    a1 = __builtin_amdgcn_mfma_f32_16x16x32_f16(x1, b, a1, 0, 0, 0);
    a2 = __builtin_amdgcn_mfma_f32_16x16x32_f16(x2, b, a2, 0, 0, 0);
    a3 = __builtin_amdgcn_mfma_f32_16x16x32_f16(x3, b, a3, 0, 0, 0);
}

// x fp32 [64][K] -> fp16 (lossless: x was fp16) in A-fragment order:
// xf[g][st][mt][lane][8]
__global__ __launch_bounds__(256)
void xpack_kernel(const float* __restrict__ x, unsigned short* __restrict__ xf, int K) {
    int c    = blockIdx.x * 256 + threadIdx.x;     // one 16 B chunk per thread
    int g    = c >> 10;
    int st   = (c >> 8) & 3;
    int mt   = (c >> 6) & 3;
    int lane = c & 63;
    int quad = lane >> 4, l15 = lane & 15;
    const float* p = x + (size_t)(l15 + mt * 16) * K + g * 128 + st * 32 + quad * 8;
    f32x4 lo = *(const f32x4*)p;
    f32x4 hi = *(const f32x4*)(p + 4);
    f16x8 r = { (_Float16)lo[0], (_Float16)lo[1], (_Float16)lo[2], (_Float16)lo[3],
                (_Float16)hi[0], (_Float16)hi[1], (_Float16)hi[2], (_Float16)hi[3] };
    *(short8*)(xf + (size_t)c * 8) = __builtin_bit_cast(short8, r);
}

// scales [N][ng] -> [ng][N] (write-coalesced)
__global__ __launch_bounds__(256)
void strans_kernel(const float* __restrict__ sc, float* __restrict__ sct, int N, int ng) {
    int n = blockIdx.x * 256 + threadIdx.x;
    int g = blockIdx.y;
    sct[(size_t)g * N + n] = sc[(size_t)n * ng + g];
}

__global__ __launch_bounds__(256)
void int4mm_kernel(const unsigned short* __restrict__ xf,  // fp16 frag-ordered x
                   const int*   __restrict__ wp,           // [N][K/2]
                   const float* __restrict__ sc,           // [N][ng] (fallback)
                   const float* __restrict__ sct,          // [ng][N] or nullptr
                   const float* __restrict__ bias,         // [N]
                   float*       __restrict__ out,          // [64][N]
                   int K, int N)
{
    __shared__ i32x4 ldsq[5120];                   // 80 KB: W 3x16K | X 2x16K
    char* w0 = (char*)ldsq;                        // W(g)   (read)
    char* w1 = w0 + 16384;                         // W(g+1) (in flight)
    char* w2 = w0 + 32768;                         // W(g+2) (stage target)
    char* ldsX = w0 + 49152;                       // X double buffer

    const int lane = threadIdx.x & 63;
    const int wave = threadIdx.x >> 6;
    const int quad = lane >> 4;
    const int l15  = lane & 15;
    const int blk64 = blockIdx.x * 64;
    const int n    = blk64 + wave * 16 + l15;      // this lane's N column
    const int ng   = K / 128;                      // 64 groups

    const char* wp8 = (const char*)wp;             // W row = 16384 B; group = 256 B

    // Stage sources (per lane): stage instr j of wave w writes LDS slots
    // S = (w*4+j)*64 + lane; slot (c=S>>4, s=S&15) holds global chunk
    // (s ^ (c&15)) of col c -> col = w*16+j*4+quad, chunk = l15 ^ (j*4+quad).
    unsigned woff[4];
    #pragma unroll
    for (int j = 0; j < 4; ++j) {
        int cloc  = wave * 16 + j * 4 + quad;
        int chunk = l15 ^ (j * 4 + quad);
        woff[j] = ((unsigned)(blk64 + cloc) << 14) + ((unsigned)chunk << 4);
    }

    // Swizzled W ds_read offsets: reader col c = wave*16+l15; chunk (quad+4t)
    // lives at slot ((quad+4t) ^ l15) -> conflict-free (8 beats/instr).
    const int cbase = (wave * 16 + l15) * 256;
    const int rd0 = cbase + (((quad + 0)  ^ l15) << 4);
    const int rd1 = cbase + (((quad + 4)  ^ l15) << 4);
    const int rd2 = cbase + (((quad + 8)  ^ l15) << 4);
    const int rd3 = cbase + (((quad + 12) ^ l15) << 4);

    f32x4 acc0 = {0.f, 0.f, 0.f, 0.f};
    f32x4 acc1 = {0.f, 0.f, 0.f, 0.f};
    f32x4 acc2 = {0.f, 0.f, 0.f, 0.f};
    f32x4 acc3 = {0.f, 0.f, 0.f, 0.f};

    // Prologue (13 VMEM, exact order for vmcnt ranks): sc0, W0x4, X0x4, W1x4.
    float s_cur = sct ? sct[n] : sc[(size_t)n * ng];
    #pragma unroll
    for (int j = 0; j < 4; ++j)
        gload_lds16(wp8 + woff[j], w0 + (wave * 4 + j) * 1024);
    {
        const char* xs = (const char*)xf + wave * 4096 + lane * 16;
        char* xd = ldsX + wave * 4096;
        #pragma unroll
        for (int j = 0; j < 4; ++j)
            gload_lds16(xs + j * 1024, xd + j * 1024);
    }
    #pragma unroll
    for (int j = 0; j < 4; ++j)
        gload_lds16(wp8 + woff[j] + 256, w1 + (wave * 4 + j) * 1024);

    // Main loop. Per iter 9 VMEM in order [X(g+1)x4, sc(g+1), W(g+2)x4];
    // s_waitcnt vmcnt(13) forces {X(g), sc(g), W(g)} complete while leaving
    // the newest 13 = {W(g+1)x4, X(g+1)x4, sc(g+1), W(g+2)x4} in flight
    // -> weights have TWO full iterations of latency cover.
    #pragma unroll 1
    for (int g = 0; g < ng; ++g) {
        const int p  = g & 1;
        const int gx = (g + 1 < ng) ? g + 1 : ng - 1;   // clamped tail restage
        const int gw = (g + 2 < ng) ? g + 2 : ng - 1;   // (dead buffers)

        __builtin_amdgcn_s_barrier();       // buffers being overwritten are free

        {   // stage X(g+1) -> ldsX[p^1]
            const char* xs = (const char*)xf + (size_t)gx * 16384
                           + wave * 4096 + lane * 16;
            char* xd = ldsX + (p ^ 1) * 16384 + wave * 4096;
            #pragma unroll
            for (int j = 0; j < 4; ++j)
                gload_lds16(xs + j * 1024, xd + j * 1024);
        }
        float s_nxt = sct ? sct[(size_t)gx * N + n] : sc[(size_t)n * ng + gx];
        {   // stage W(g+2) -> w2
            #pragma unroll
            for (int j = 0; j < 4; ++j)
                gload_lds16(wp8 + woff[j] + (size_t)gw * 256,
                            w2 + (wave * 4 + j) * 1024);
        }

        asm volatile("s_waitcnt vmcnt(13)" ::: "memory");
        __builtin_amdgcn_s_barrier();
        __builtin_amdgcn_sched_barrier(0);  // keep ds_reads below the sync

        const f16x2 s2 = {(_Float16)s_cur, (_Float16)s_cur};
        i32x4 v0 = *(const i32x4*)(w0 + rd0);
        i32x4 v1 = *(const i32x4*)(w0 + rd1);
        i32x4 v2 = *(const i32x4*)(w0 + rd2);
        i32x4 v3 = *(const i32x4*)(w0 + rd3);

        const char* xb = ldsX + p * 16384;
        kstep(v0, s2, xb,         lane, acc0, acc1, acc2, acc3);
        kstep(v1, s2, xb +  4096, lane, acc0, acc1, acc2, acc3);
        kstep(v2, s2, xb +  8192, lane, acc0, acc1, acc2, acc3);
        kstep(v3, s2, xb + 12288, lane, acc0, acc1, acc2, acc3);

        char* wt = w0; w0 = w1; w1 = w2; w2 = wt;   // rotate W buffers
        s_cur = s_nxt;
    }

    // Epilogue. C/D layout (m89-verified): col = lane&15 (= n), row = quad*4 + reg.
    const float bv = bias[n];
    float* orow = out + (size_t)(quad * 4) * N + n;
    #pragma unroll
    for (int r = 0; r < 4; ++r) {
        orow[(size_t)(r)      * N] = acc0[r] + bv;
        orow[(size_t)(r + 16) * N] = acc1[r] + bv;
        orow[(size_t)(r + 32) * N] = acc2[r] + bv;
        orow[(size_t)(r + 48) * N] = acc3[r] + bv;
    }
}

extern "C" void kernel_launch(void* const* d_in, const int* in_sizes, int n_in,
                              void* d_out, int out_size, void* d_ws, size_t ws_size,
                              hipStream_t stream)
{
    const float* x    = (const float*)d_in[0];
    const int*   wp   = (const int*)d_in[1];
    const float* sc   = (const float*)d_in[2];
    const float* bias = (const float*)d_in[3];
    float*       out  = (float*)d_out;

    const int N  = in_sizes[3];                       // 28672
    const long long Kh = (long long)in_sizes[1] / N;  // 4096
    const int K  = (int)(2 * Kh);                     // 8192
    const int ng = K / 128;                           // 64

    unsigned short* xf = (unsigned short*)d_ws;       // 1 MB frag-ordered fp16 x
    const size_t xf_bytes  = (size_t)ng * 16384;
    const size_t sct_bytes = (size_t)ng * N * 4;
    float* sct = nullptr;

    xpack_kernel<<<(ng * 1024) / 256, 256, 0, stream>>>(x, xf, K);
    if (ws_size >= xf_bytes + sct_bytes && (N & 255) == 0) {
        sct = (float*)((char*)d_ws + xf_bytes);
        strans_kernel<<<dim3(N / 256, ng), 256, 0, stream>>>(sc, sct, N, ng);
    }
    int4mm_kernel<<<N / 64, 256, 0, stream>>>(xf, wp, sc, sct, bias, out, K, N);
}